// Round 1
// baseline (4034.484 us; speedup 1.0000x reference)
//
#include <hip/hip_runtime.h>
#include <math.h>

constexpr int kDM   = 512;
constexpr int kDI   = 1024;
constexpr int kDS   = 16;
constexpr int kDC   = 4;
constexpr int kDTR  = 32;
constexpr int kL    = 2;
constexpr int kB    = 4;
constexpr int kN    = 1024;
constexpr int kB2   = 8;              // combined batch: rows 0-3 fwd, 4-7 bwd
constexpr int kROWS = kB2 * kN;       // 8192
constexpr int kMDIR = kB * kN;        // 4096 rows per direction

enum { EPI_NONE=0, EPI_SOFTPLUS=1, EPI_RESID=2, EPI_GELU=3, EPI_RESID_BIAS=4, EPI_TANH=5 };

// ---------------------------------------------------------------- init h ----
__global__ __launch_bounds__(256) void init_h_k(const float* __restrict__ x,
                                                float* __restrict__ h)
{
    size_t idx = (size_t)blockIdx.x * 256 + threadIdx.x;   // kROWS*kDM
    int d  = idx & (kDM - 1);
    int t  = (idx >> 9) & (kN - 1);
    int bb = (int)(idx >> 19);
    int b = bb & 3, dir = bb >> 2;
    int ts = dir ? (kN - 1 - t) : t;
    h[idx] = x[((size_t)b * kN + ts) * kDM + d];
}

// ---------------------------------------------------------------- layernorm --
template<int DIM>
__global__ __launch_bounds__(256) void ln_k(const float* __restrict__ x,
    const float* __restrict__ wf, const float* __restrict__ wb,
    const float* __restrict__ bf, const float* __restrict__ bbp,
    float* __restrict__ out)
{
    const int row = blockIdx.x;
    const int tid = threadIdx.x;
    constexpr int PT = DIM / 256;
    const int dir = (row >= kMDIR) ? 1 : 0;
    const float* w = dir ? wb : wf;
    const float* b = dir ? bbp : bf;

    float v[PT];
    float s1 = 0.f, s2 = 0.f;
#pragma unroll
    for (int i = 0; i < PT; i++) {
        float t = x[(size_t)row * DIM + tid + i * 256];
        v[i] = t; s1 += t; s2 += t * t;
    }
    for (int o = 32; o > 0; o >>= 1) { s1 += __shfl_xor(s1, o, 64); s2 += __shfl_xor(s2, o, 64); }
    __shared__ float r1[4], r2[4];
    int wv = tid >> 6;
    if ((tid & 63) == 0) { r1[wv] = s1; r2[wv] = s2; }
    __syncthreads();
    s1 = r1[0] + r1[1] + r1[2] + r1[3];
    s2 = r2[0] + r2[1] + r2[2] + r2[3];
    float mu  = s1 / DIM;
    float var = s2 / DIM - mu * mu;
    float rr  = rsqrtf(var + 1e-5f);
#pragma unroll
    for (int i = 0; i < PT; i++) {
        int c = tid + i * 256;
        out[(size_t)row * DIM + c] = (v[i] - mu) * rr * w[c] + b[c];
    }
}

// ---------------------------------------------------------------- GEMM ------
// C[M x N] = A[M x K (lda)] @ B[K x N] (+bias)(+epilogue). Row-major.
// Weight/bias pointers per direction; dir decided by row block.
template<int BM, int BN, int BK, int TM, int TN, int EPI>
__global__ __launch_bounds__(256) void gemm_ep(
    const float* __restrict__ A, int lda, int K,
    const float* __restrict__ Bf, const float* __restrict__ Bbk,
    const float* __restrict__ biasf, const float* __restrict__ biasb,
    float* C, int N)
{
    __shared__ float As[BK][BM];
    __shared__ float Bs[BK][BN];
    const int tid  = threadIdx.x;
    const int n0   = blockIdx.x * BN;
    const int row0 = blockIdx.y * BM;
    const int dir  = (row0 >= kMDIR) ? 1 : 0;
    const float* __restrict__ Bmat = dir ? Bbk : Bf;
    const float* bias = dir ? biasb : biasf;

    const int a_m = (tid * 4) / BK;
    const int a_k = (tid * 4) % BK;
    const int b_k = (tid * 4) / BN;
    const int b_n = (tid * 4) % BN;

    const int tcol = tid % (BN / TN);
    const int trow = tid / (BN / TN);

    float acc[TM][TN];
#pragma unroll
    for (int i = 0; i < TM; i++)
#pragma unroll
        for (int j = 0; j < TN; j++) acc[i][j] = 0.f;

    for (int kt = 0; kt < K; kt += BK) {
        float4 a4 = *(const float4*)(A + (size_t)(row0 + a_m) * lda + kt + a_k);
        float4 b4 = *(const float4*)(Bmat + (size_t)(kt + b_k) * N + n0 + b_n);
        As[a_k + 0][a_m] = a4.x; As[a_k + 1][a_m] = a4.y;
        As[a_k + 2][a_m] = a4.z; As[a_k + 3][a_m] = a4.w;
        *(float4*)&Bs[b_k][b_n] = b4;
        __syncthreads();
#pragma unroll
        for (int kk = 0; kk < BK; kk++) {
            float ar[TM], br[TN];
#pragma unroll
            for (int i = 0; i < TM; i += 4) *(float4*)&ar[i] = *(const float4*)&As[kk][trow * TM + i];
#pragma unroll
            for (int j = 0; j < TN; j += 4) *(float4*)&br[j] = *(const float4*)&Bs[kk][tcol * TN + j];
#pragma unroll
            for (int i = 0; i < TM; i++)
#pragma unroll
                for (int j = 0; j < TN; j++)
                    acc[i][j] += ar[i] * br[j];
        }
        __syncthreads();
    }
#pragma unroll
    for (int i = 0; i < TM; i++) {
        int row = row0 + trow * TM + i;
#pragma unroll
        for (int j = 0; j < TN; j++) {
            int col = n0 + tcol * TN + j;
            float v = acc[i][j];
            if (EPI == EPI_SOFTPLUS || EPI == EPI_GELU || EPI == EPI_RESID_BIAS || EPI == EPI_TANH)
                v += bias[col];
            size_t o = (size_t)row * N + col;
            if      (EPI == EPI_NONE)       C[o] = v;
            else if (EPI == EPI_SOFTPLUS)   C[o] = (v > 20.f) ? v : __logf(1.f + __expf(v));
            else if (EPI == EPI_RESID)      C[o] += v;
            else if (EPI == EPI_RESID_BIAS) C[o] += v;
            else if (EPI == EPI_GELU)       C[o] = 0.5f * v * (1.f + erff(v * 0.70710678118654752f));
            else if (EPI == EPI_TANH)       C[o] = tanhf(v);
        }
    }
}

// ---------------------------------------------------------------- conv+silu -
__global__ __launch_bounds__(256) void conv_silu_k(const float* __restrict__ xz,
    const float* __restrict__ cwf, const float* __restrict__ cwb,
    const float* __restrict__ cbf, const float* __restrict__ cbb,
    float* __restrict__ xh)
{
    size_t idx = (size_t)blockIdx.x * 256 + threadIdx.x;  // kROWS*kDI
    int d  = idx & (kDI - 1);
    int t  = (idx >> 10) & (kN - 1);
    int bb = (int)(idx >> 20);
    int dir = bb >> 2;
    const float* cw = dir ? cwb : cwf;
    const float* cb = dir ? cbb : cbf;
    float acc = cb[d];
    long long base = ((long long)bb * kN + t) * (2 * kDI) + d;
#pragma unroll
    for (int k = 0; k < kDC; k++) {
        int ts = t - (kDC - 1) + k;
        if (ts >= 0)
            acc += cw[d * kDC + k] * xz[base + (long long)(k - (kDC - 1)) * (2 * kDI)];
    }
    xh[idx] = acc * (1.f / (1.f + __expf(-acc)));
}

// ---------------------------------------------------------------- scan ------
// thread = (bb, d, s); 16 s-lanes per d; y written in-place over dt buffer.
__global__ __launch_bounds__(256) void scan_k(
    float* dty,                       // in: dt, out: y (same buffer)
    const float* __restrict__ xh,
    const float* __restrict__ dbl,
    const float* __restrict__ xz,
    const float* __restrict__ alogf, const float* __restrict__ alogb,
    const float* __restrict__ ddf,   const float* __restrict__ ddb)
{
    int blk  = blockIdx.x;            // 512 blocks
    int bb   = blk >> 6;
    int dgrp = blk & 63;
    int s    = threadIdx.x & 15;
    int dloc = threadIdx.x >> 4;
    int d    = dgrp * 16 + dloc;
    int dir  = bb >> 2;
    const float* alog = dir ? alogb : alogf;
    const float* ddp  = dir ? ddb : ddf;
    float a   = -__expf(alog[d * kDS + s]);
    float ddv = ddp[d];
    float hst = 0.f;
    size_t rbase = (size_t)bb * kN;
    for (int t = 0; t < kN; t++) {
        size_t row = rbase + t;
        float dt = dty[row * kDI + d];
        float xv = xh[row * kDI + d];
        float Bv = dbl[row * 64 + kDTR + s];
        float Cv = dbl[row * 64 + kDTR + kDS + s];
        hst = __expf(dt * a) * hst + (dt * xv) * Bv;
        float p = hst * Cv;
        p += __shfl_xor(p, 1, 16);
        p += __shfl_xor(p, 2, 16);
        p += __shfl_xor(p, 4, 16);
        p += __shfl_xor(p, 8, 16);
        if (s == 0) {
            float zv = xz[row * (2 * kDI) + kDI + d];
            dty[row * kDI + d] = (p + ddv * xv) * (zv * (1.f / (1.f + __expf(-zv))));
        }
    }
}

// ---------------------------------------------------------------- attention -
__global__ __launch_bounds__(64) void att_score_k(const float* __restrict__ tmp,
    const float* __restrict__ aw2, const float* __restrict__ ab2,
    float* __restrict__ score)
{
    int row = blockIdx.x, lane = threadIdx.x;
    float acc = 0.f;
#pragma unroll
    for (int j = 0; j < 4; j++)
        acc += tmp[(size_t)row * 256 + lane + j * 64] * aw2[lane + j * 64];
    for (int o = 32; o > 0; o >>= 1) acc += __shfl_xor(acc, o, 64);
    if (lane == 0) score[row] = acc + ab2[0];
}

__global__ __launch_bounds__(256) void softmax_k(const float* __restrict__ score,
                                                 float* __restrict__ w)
{
    int bb = blockIdx.x, tid = threadIdx.x;
    float v[4]; float m = -1e30f;
#pragma unroll
    for (int i = 0; i < 4; i++) { v[i] = score[bb * kN + tid + i * 256]; m = fmaxf(m, v[i]); }
    for (int o = 32; o > 0; o >>= 1) m = fmaxf(m, __shfl_xor(m, o, 64));
    __shared__ float r1[4], r2[4];
    int wv = tid >> 6;
    if ((tid & 63) == 0) r1[wv] = m;
    __syncthreads();
    m = fmaxf(fmaxf(r1[0], r1[1]), fmaxf(r1[2], r1[3]));
    float s = 0.f;
#pragma unroll
    for (int i = 0; i < 4; i++) { v[i] = __expf(v[i] - m); s += v[i]; }
    for (int o = 32; o > 0; o >>= 1) s += __shfl_xor(s, o, 64);
    if ((tid & 63) == 0) r2[wv] = s;
    __syncthreads();
    s = r2[0] + r2[1] + r2[2] + r2[3];
    float inv = 1.f / s;
#pragma unroll
    for (int i = 0; i < 4; i++) w[bb * kN + tid + i * 256] = v[i] * inv;
}

__global__ __launch_bounds__(512) void pool_k(const float* __restrict__ w,
    const float* __restrict__ h, float* zcat)
{
    int bb = blockIdx.x, chunk = blockIdx.y;   // 8 x 32
    int d = threadIdx.x;
    float acc = 0.f;
    int n0 = chunk * 32;
    for (int n = n0; n < n0 + 32; n++)
        acc += w[bb * kN + n] * h[((size_t)bb * kN + n) * kDM + d];
    int b = bb & 3, dir = bb >> 2;
    atomicAdd(&zcat[b * (2 * kDM) + dir * kDM + d], acc);
}

__global__ __launch_bounds__(256) void att_out_k(const float* __restrict__ w,
                                                 float* __restrict__ out)
{
    int idx = blockIdx.x * 256 + threadIdx.x;  // kB*kN
    int b = idx >> 10, n = idx & 1023;
    out[idx] = 0.5f * (w[b * kN + n] + w[(b + 4) * kN + (kN - 1 - n)]);
}

// ---------------------------------------------------------------- launch ----
extern "C" void kernel_launch(void* const* d_in, const int* in_sizes, int n_in,
                              void* d_out, int out_size, void* d_ws, size_t ws_size,
                              hipStream_t stream)
{
    const float* x = (const float*)d_in[0];
    const float* fp[17]; const float* bp[17];
    for (int i = 0; i < 17; i++) { fp[i] = (const float*)d_in[1 + i]; bp[i] = (const float*)d_in[18 + i]; }
    const float* aw1 = (const float*)d_in[35];
    const float* ab1 = (const float*)d_in[36];
    const float* aw2 = (const float*)d_in[37];
    const float* ab2 = (const float*)d_in[38];
    const float* nw  = (const float*)d_in[39];
    const float* nb  = (const float*)d_in[40];
    float* out = (float*)d_out;

    float* ws    = (float*)d_ws;
    float* h     = ws;                               // 8192*512
    float* u     = h    + (size_t)kROWS * kDM;       // 8192*512
    float* xz    = u    + (size_t)kROWS * kDM;       // 8192*2048
    float* xh    = xz   + (size_t)kROWS * 2 * kDI;   // 8192*1024
    float* dbl   = xh   + (size_t)kROWS * kDI;       // 8192*64
    float* dty   = dbl  + (size_t)kROWS * 64;        // 8192*1024
    float* score = dty  + (size_t)kROWS * kDI;       // 8192
    float* smw   = score + kROWS;                    // 8192
    float* zcat  = smw  + kROWS;                     // 4096

    init_h_k<<<kROWS * kDM / 256, 256, 0, stream>>>(x, h);

    for (int l = 0; l < kL; l++) {
        const float *f_n1w = fp[0]  + l * kDM,            *b_n1w = bp[0]  + l * kDM;
        const float *f_n1b = fp[1]  + l * kDM,            *b_n1b = bp[1]  + l * kDM;
        const float *f_inw = fp[2]  + l * kDM * 2 * kDI,  *b_inw = bp[2]  + l * kDM * 2 * kDI;
        const float *f_cw  = fp[3]  + l * kDI * kDC,      *b_cw  = bp[3]  + l * kDI * kDC;
        const float *f_cb  = fp[4]  + l * kDI,            *b_cb  = bp[4]  + l * kDI;
        const float *f_xpw = fp[5]  + l * kDI * 64,       *b_xpw = bp[5]  + l * kDI * 64;
        const float *f_dtw = fp[6]  + l * kDTR * kDI,     *b_dtw = bp[6]  + l * kDTR * kDI;
        const float *f_dtb = fp[7]  + l * kDI,            *b_dtb = bp[7]  + l * kDI;
        const float *f_alog= fp[8]  + l * kDI * kDS,      *b_alog= bp[8]  + l * kDI * kDS;
        const float *f_dd  = fp[9]  + l * kDI,            *b_dd  = bp[9]  + l * kDI;
        const float *f_ow  = fp[10] + l * kDI * kDM,      *b_ow  = bp[10] + l * kDI * kDM;
        const float *f_n2w = fp[11] + l * kDM,            *b_n2w = bp[11] + l * kDM;
        const float *f_n2b = fp[12] + l * kDM,            *b_n2b = bp[12] + l * kDM;
        const float *f_w1  = fp[13] + l * kDM * 4 * kDM,  *b_w1  = bp[13] + l * kDM * 4 * kDM;
        const float *f_b1  = fp[14] + l * 4 * kDM,        *b_b1  = bp[14] + l * 4 * kDM;
        const float *f_w2  = fp[15] + l * 4 * kDM * kDM,  *b_w2  = bp[15] + l * 4 * kDM * kDM;
        const float *f_b2  = fp[16] + l * kDM,            *b_b2  = bp[16] + l * kDM;

        // u = LN1(h)
        ln_k<kDM><<<kROWS, 256, 0, stream>>>(h, f_n1w, b_n1w, f_n1b, b_n1b, u);
        // xz = u @ in_w
        gemm_ep<128,128,8,8,8,EPI_NONE><<<dim3(2*kDI/128, kROWS/128), 256, 0, stream>>>(
            u, kDM, kDM, f_inw, b_inw, nullptr, nullptr, xz, 2*kDI);
        // xh = silu(causal depthwise conv(xz[:, :DI]) + cb)
        conv_silu_k<<<kROWS * kDI / 256, 256, 0, stream>>>(xz, f_cw, b_cw, f_cb, b_cb, xh);
        // dbl = xh @ xpw
        gemm_ep<64,64,16,4,4,EPI_NONE><<<dim3(64/64, kROWS/64), 256, 0, stream>>>(
            xh, kDI, kDI, f_xpw, b_xpw, nullptr, nullptr, dbl, 64);
        // dt = softplus(dbl[:, :32] @ dtw + dtb)
        gemm_ep<128,128,8,8,8,EPI_SOFTPLUS><<<dim3(kDI/128, kROWS/128), 256, 0, stream>>>(
            dbl, 64, kDTR, f_dtw, b_dtw, f_dtb, b_dtb, dty, kDI);
        // selective scan -> y (in-place into dty), gated by silu(z)
        scan_k<<<kB2 * kDI / 16, 256, 0, stream>>>(dty, xh, dbl, xz, f_alog, b_alog, f_dd, b_dd);
        // h += y @ ow
        gemm_ep<128,128,8,8,8,EPI_RESID><<<dim3(kDM/128, kROWS/128), 256, 0, stream>>>(
            dty, kDI, kDI, f_ow, b_ow, nullptr, nullptr, h, kDM);
        // u = LN2(h)
        ln_k<kDM><<<kROWS, 256, 0, stream>>>(h, f_n2w, b_n2w, f_n2b, b_n2b, u);
        // xz = gelu(u @ w1 + b1)
        gemm_ep<128,128,8,8,8,EPI_GELU><<<dim3(4*kDM/128, kROWS/128), 256, 0, stream>>>(
            u, kDM, kDM, f_w1, b_w1, f_b1, b_b1, xz, 4*kDM);
        // h += xz @ w2 + b2
        gemm_ep<128,128,8,8,8,EPI_RESID_BIAS><<<dim3(kDM/128, kROWS/128), 256, 0, stream>>>(
            xz, 4*kDM, 4*kDM, f_w2, b_w2, f_b2, b_b2, h, kDM);
    }

    // attention scores: u[:, :256] = tanh(h @ aw1 + ab1)
    gemm_ep<128,128,8,8,8,EPI_TANH><<<dim3(256/128, kROWS/128), 256, 0, stream>>>(
        h, kDM, kDM, aw1, aw1, ab1, ab1, u, 256);
    att_score_k<<<kROWS, 64, 0, stream>>>(u, aw2, ab2, score);
    softmax_k<<<kB2, 256, 0, stream>>>(score, smw);
    hipMemsetAsync(zcat, 0, kB * 2 * kDM * sizeof(float), stream);
    pool_k<<<dim3(kB2, 32), 512, 0, stream>>>(smw, h, zcat);
    // out[0:4096] = LN(concat(zf, zb))
    ln_k<2*kDM><<<kB, 256, 0, stream>>>(zcat, nw, nw, nb, nb, out);
    // out[4096:8192] = 0.5*(af + flip(ab))
    att_out_k<<<kB * kN / 256, 256, 0, stream>>>(smw, out + kB * 2 * kDM);
}

// Round 2
// 2767.023 us; speedup vs baseline: 1.4581x; 1.4581x over previous
//
#include <hip/hip_runtime.h>
#include <math.h>

constexpr int kDM   = 512;
constexpr int kDI   = 1024;
constexpr int kDS   = 16;
constexpr int kDC   = 4;
constexpr int kDTR  = 32;
constexpr int kL    = 2;
constexpr int kB    = 4;
constexpr int kN    = 1024;
constexpr int kB2   = 8;              // combined batch: rows 0-3 fwd, 4-7 bwd
constexpr int kROWS = kB2 * kN;       // 8192
constexpr int kMDIR = kB * kN;        // 4096 rows per direction

enum { EPI_NONE=0, EPI_SOFTPLUS=1, EPI_RESID=2, EPI_GELU=3, EPI_RESID_BIAS=4, EPI_TANH=5 };

// ---------------------------------------------------------------- init h ----
__global__ __launch_bounds__(256) void init_h_k(const float* __restrict__ x,
                                                float* __restrict__ h)
{
    size_t idx = (size_t)blockIdx.x * 256 + threadIdx.x;   // kROWS*kDM
    int d  = idx & (kDM - 1);
    int t  = (idx >> 9) & (kN - 1);
    int bb = (int)(idx >> 19);
    int b = bb & 3, dir = bb >> 2;
    int ts = dir ? (kN - 1 - t) : t;
    h[idx] = x[((size_t)b * kN + ts) * kDM + d];
}

// ---------------------------------------------------------------- layernorm --
template<int DIM>
__global__ __launch_bounds__(256) void ln_k(const float* __restrict__ x,
    const float* __restrict__ wf, const float* __restrict__ wb,
    const float* __restrict__ bf, const float* __restrict__ bbp,
    float* __restrict__ out)
{
    const int row = blockIdx.x;
    const int tid = threadIdx.x;
    constexpr int PT = DIM / 256;
    const int dir = (row >= kMDIR) ? 1 : 0;
    const float* w = dir ? wb : wf;
    const float* b = dir ? bbp : bf;

    float v[PT];
    float s1 = 0.f, s2 = 0.f;
#pragma unroll
    for (int i = 0; i < PT; i++) {
        float t = x[(size_t)row * DIM + tid + i * 256];
        v[i] = t; s1 += t; s2 += t * t;
    }
    for (int o = 32; o > 0; o >>= 1) { s1 += __shfl_xor(s1, o, 64); s2 += __shfl_xor(s2, o, 64); }
    __shared__ float r1[4], r2[4];
    int wv = tid >> 6;
    if ((tid & 63) == 0) { r1[wv] = s1; r2[wv] = s2; }
    __syncthreads();
    s1 = r1[0] + r1[1] + r1[2] + r1[3];
    s2 = r2[0] + r2[1] + r2[2] + r2[3];
    float mu  = s1 / DIM;
    float var = s2 / DIM - mu * mu;
    float rr  = rsqrtf(var + 1e-5f);
#pragma unroll
    for (int i = 0; i < PT; i++) {
        int c = tid + i * 256;
        out[(size_t)row * DIM + c] = (v[i] - mu) * rr * w[c] + b[c];
    }
}

// ---------------------------------------------------------------- GEMM ------
// C[M x N] = A[M x K (lda)] @ B[K x N] (+bias)(+epilogue). Row-major.
// Weight/bias pointers per direction; dir decided by row block.
template<int BM, int BN, int BK, int TM, int TN, int EPI>
__global__ __launch_bounds__(256) void gemm_ep(
    const float* __restrict__ A, int lda, int K,
    const float* __restrict__ Bf, const float* __restrict__ Bbk,
    const float* __restrict__ biasf, const float* __restrict__ biasb,
    float* C, int N)
{
    __shared__ float As[BK][BM];
    __shared__ float Bs[BK][BN];
    const int tid  = threadIdx.x;
    const int n0   = blockIdx.x * BN;
    const int row0 = blockIdx.y * BM;
    const int dir  = (row0 >= kMDIR) ? 1 : 0;
    const float* __restrict__ Bmat = dir ? Bbk : Bf;
    const float* bias = dir ? biasb : biasf;

    const int a_m = (tid * 4) / BK;
    const int a_k = (tid * 4) % BK;
    const int b_k = (tid * 4) / BN;
    const int b_n = (tid * 4) % BN;

    const int tcol = tid % (BN / TN);
    const int trow = tid / (BN / TN);

    float acc[TM][TN];
#pragma unroll
    for (int i = 0; i < TM; i++)
#pragma unroll
        for (int j = 0; j < TN; j++) acc[i][j] = 0.f;

    for (int kt = 0; kt < K; kt += BK) {
        float4 a4 = *(const float4*)(A + (size_t)(row0 + a_m) * lda + kt + a_k);
        float4 b4 = *(const float4*)(Bmat + (size_t)(kt + b_k) * N + n0 + b_n);
        As[a_k + 0][a_m] = a4.x; As[a_k + 1][a_m] = a4.y;
        As[a_k + 2][a_m] = a4.z; As[a_k + 3][a_m] = a4.w;
        *(float4*)&Bs[b_k][b_n] = b4;
        __syncthreads();
#pragma unroll
        for (int kk = 0; kk < BK; kk++) {
            float ar[TM], br[TN];
#pragma unroll
            for (int i = 0; i < TM; i += 4) *(float4*)&ar[i] = *(const float4*)&As[kk][trow * TM + i];
#pragma unroll
            for (int j = 0; j < TN; j += 4) *(float4*)&br[j] = *(const float4*)&Bs[kk][tcol * TN + j];
#pragma unroll
            for (int i = 0; i < TM; i++)
#pragma unroll
                for (int j = 0; j < TN; j++)
                    acc[i][j] += ar[i] * br[j];
        }
        __syncthreads();
    }
#pragma unroll
    for (int i = 0; i < TM; i++) {
        int row = row0 + trow * TM + i;
#pragma unroll
        for (int j = 0; j < TN; j++) {
            int col = n0 + tcol * TN + j;
            float v = acc[i][j];
            if (EPI == EPI_SOFTPLUS || EPI == EPI_GELU || EPI == EPI_RESID_BIAS || EPI == EPI_TANH)
                v += bias[col];
            size_t o = (size_t)row * N + col;
            if      (EPI == EPI_NONE)       C[o] = v;
            else if (EPI == EPI_SOFTPLUS)   C[o] = (v > 20.f) ? v : __logf(1.f + __expf(v));
            else if (EPI == EPI_RESID)      C[o] += v;
            else if (EPI == EPI_RESID_BIAS) C[o] += v;
            else if (EPI == EPI_GELU)       C[o] = 0.5f * v * (1.f + erff(v * 0.70710678118654752f));
            else if (EPI == EPI_TANH)       C[o] = tanhf(v);
        }
    }
}

// ---------------------------------------------------------------- conv+silu -
__global__ __launch_bounds__(256) void conv_silu_k(const float* __restrict__ xz,
    const float* __restrict__ cwf, const float* __restrict__ cwb,
    const float* __restrict__ cbf, const float* __restrict__ cbb,
    float* __restrict__ xh)
{
    size_t idx = (size_t)blockIdx.x * 256 + threadIdx.x;  // kROWS*kDI
    int d  = idx & (kDI - 1);
    int t  = (idx >> 10) & (kN - 1);
    int bb = (int)(idx >> 20);
    int dir = bb >> 2;
    const float* cw = dir ? cwb : cwf;
    const float* cb = dir ? cbb : cbf;
    float acc = cb[d];
    long long base = ((long long)bb * kN + t) * (2 * kDI) + d;
#pragma unroll
    for (int k = 0; k < kDC; k++) {
        int ts = t - (kDC - 1) + k;
        if (ts >= 0)
            acc += cw[d * kDC + k] * xz[base + (long long)(k - (kDC - 1)) * (2 * kDI)];
    }
    xh[idx] = acc * (1.f / (1.f + __expf(-acc)));
}

// ---------------------------------------------------------------- scan ------
// thread = (bb, d, s); 16 s-lanes per d (DPP rows align with s-groups).
// dt is read from dtp (read-only); y is written into the dead x-half of xz
// (disjoint from the z-half we read) so every pointer is truly __restrict
// and the compiler never store-drains between chunks.
constexpr int kTC = 8;            // timesteps prefetched per chunk
constexpr int kNC = kN / kTC;     // 128 chunks

struct ScanChunk { float dt[kTC], xv[kTC], Bv[kTC], Cv[kTC], zv[kTC]; };

template<int CTRL>
__device__ __forceinline__ float dpp_add(float x) {
    int m = __builtin_amdgcn_update_dpp(0, __float_as_int(x), CTRL, 0xF, 0xF, true);
    return x + __int_as_float(m);
}

__device__ __forceinline__ void scan_load(
    const float* __restrict__ dtp, const float* __restrict__ xh,
    const float* __restrict__ dbl, const float* __restrict__ zsrc,
    size_t rbase, int t0, int d, int s, ScanChunk& ck)
{
#pragma unroll
    for (int j = 0; j < kTC; j++) {
        size_t row = rbase + t0 + j;
        ck.dt[j] = dtp[row * kDI + d];
        ck.xv[j] = xh[row * kDI + d];
        ck.Bv[j] = dbl[row * 64 + kDTR + s];
        ck.Cv[j] = dbl[row * 64 + kDTR + kDS + s];
        ck.zv[j] = zsrc[row * (2 * kDI) + d];
    }
}

__device__ __forceinline__ void scan_compute(
    float* __restrict__ ybuf, size_t rbase, int t0, int d, int s,
    float a, float ddv, float& hst, const ScanChunk& ck)
{
#pragma unroll
    for (int j = 0; j < kTC; j++) {
        float e = __expf(ck.dt[j] * a);
        hst = e * hst + (ck.dt[j] * ck.xv[j]) * ck.Bv[j];
        float p = hst * ck.Cv[j];
        p = dpp_add<0x128>(p);   // row_ror:8  (16-lane row == s-group)
        p = dpp_add<0x124>(p);   // row_ror:4
        p = dpp_add<0x122>(p);   // row_ror:2
        p = dpp_add<0x121>(p);   // row_ror:1
        if (s == 0) {
            float zv = ck.zv[j];
            size_t row = rbase + t0 + j;
            ybuf[row * (2 * kDI) + d] = (p + ddv * ck.xv[j]) * (zv / (1.f + __expf(-zv)));
        }
    }
}

__global__ __launch_bounds__(256) void scan_k(
    const float* __restrict__ dtp, const float* __restrict__ xh,
    const float* __restrict__ dbl, const float* __restrict__ zsrc,
    float* __restrict__ ybuf,
    const float* __restrict__ alogf, const float* __restrict__ alogb,
    const float* __restrict__ ddf,   const float* __restrict__ ddb)
{
    int blk  = blockIdx.x;            // 512 blocks
    int bb   = blk >> 6;
    int dgrp = blk & 63;
    int s    = threadIdx.x & 15;
    int d    = dgrp * 16 + (threadIdx.x >> 4);
    int dir  = bb >> 2;
    const float* alog = dir ? alogb : alogf;
    const float* ddp  = dir ? ddb : ddf;
    float a   = -__expf(alog[d * kDS + s]);
    float ddv = ddp[d];
    float hst = 0.f;
    size_t rbase = (size_t)bb * kN;

    ScanChunk cka, ckb;
    scan_load(dtp, xh, dbl, zsrc, rbase, 0, d, s, cka);
    for (int c = 0; c < kNC; c += 2) {
        scan_load(dtp, xh, dbl, zsrc, rbase, (c + 1) * kTC, d, s, ckb);
        scan_compute(ybuf, rbase, c * kTC, d, s, a, ddv, hst, cka);
        int tn = (c + 2 < kNC) ? (c + 2) * kTC : (kNC - 1) * kTC;  // clamped dummy on last
        scan_load(dtp, xh, dbl, zsrc, rbase, tn, d, s, cka);
        scan_compute(ybuf, rbase, (c + 1) * kTC, d, s, a, ddv, hst, ckb);
    }
}

// ---------------------------------------------------------------- attention -
__global__ __launch_bounds__(64) void att_score_k(const float* __restrict__ tmp,
    const float* __restrict__ aw2, const float* __restrict__ ab2,
    float* __restrict__ score)
{
    int row = blockIdx.x, lane = threadIdx.x;
    float acc = 0.f;
#pragma unroll
    for (int j = 0; j < 4; j++)
        acc += tmp[(size_t)row * 256 + lane + j * 64] * aw2[lane + j * 64];
    for (int o = 32; o > 0; o >>= 1) acc += __shfl_xor(acc, o, 64);
    if (lane == 0) score[row] = acc + ab2[0];
}

__global__ __launch_bounds__(256) void softmax_k(const float* __restrict__ score,
                                                 float* __restrict__ w)
{
    int bb = blockIdx.x, tid = threadIdx.x;
    float v[4]; float m = -1e30f;
#pragma unroll
    for (int i = 0; i < 4; i++) { v[i] = score[bb * kN + tid + i * 256]; m = fmaxf(m, v[i]); }
    for (int o = 32; o > 0; o >>= 1) m = fmaxf(m, __shfl_xor(m, o, 64));
    __shared__ float r1[4], r2[4];
    int wv = tid >> 6;
    if ((tid & 63) == 0) r1[wv] = m;
    __syncthreads();
    m = fmaxf(fmaxf(r1[0], r1[1]), fmaxf(r1[2], r1[3]));
    float s = 0.f;
#pragma unroll
    for (int i = 0; i < 4; i++) { v[i] = __expf(v[i] - m); s += v[i]; }
    for (int o = 32; o > 0; o >>= 1) s += __shfl_xor(s, o, 64);
    if ((tid & 63) == 0) r2[wv] = s;
    __syncthreads();
    s = r2[0] + r2[1] + r2[2] + r2[3];
    float inv = 1.f / s;
#pragma unroll
    for (int i = 0; i < 4; i++) w[bb * kN + tid + i * 256] = v[i] * inv;
}

__global__ __launch_bounds__(512) void pool_k(const float* __restrict__ w,
    const float* __restrict__ h, float* zcat)
{
    int bb = blockIdx.x, chunk = blockIdx.y;   // 8 x 32
    int d = threadIdx.x;
    float acc = 0.f;
    int n0 = chunk * 32;
    for (int n = n0; n < n0 + 32; n++)
        acc += w[bb * kN + n] * h[((size_t)bb * kN + n) * kDM + d];
    int b = bb & 3, dir = bb >> 2;
    atomicAdd(&zcat[b * (2 * kDM) + dir * kDM + d], acc);
}

__global__ __launch_bounds__(256) void att_out_k(const float* __restrict__ w,
                                                 float* __restrict__ out)
{
    int idx = blockIdx.x * 256 + threadIdx.x;  // kB*kN
    int b = idx >> 10, n = idx & 1023;
    out[idx] = 0.5f * (w[b * kN + n] + w[(b + 4) * kN + (kN - 1 - n)]);
}

// ---------------------------------------------------------------- launch ----
extern "C" void kernel_launch(void* const* d_in, const int* in_sizes, int n_in,
                              void* d_out, int out_size, void* d_ws, size_t ws_size,
                              hipStream_t stream)
{
    const float* x = (const float*)d_in[0];
    const float* fp[17]; const float* bp[17];
    for (int i = 0; i < 17; i++) { fp[i] = (const float*)d_in[1 + i]; bp[i] = (const float*)d_in[18 + i]; }
    const float* aw1 = (const float*)d_in[35];
    const float* ab1 = (const float*)d_in[36];
    const float* aw2 = (const float*)d_in[37];
    const float* ab2 = (const float*)d_in[38];
    const float* nw  = (const float*)d_in[39];
    const float* nb  = (const float*)d_in[40];
    float* out = (float*)d_out;

    float* ws    = (float*)d_ws;
    float* h     = ws;                               // 8192*512
    float* u     = h    + (size_t)kROWS * kDM;       // 8192*512
    float* xz    = u    + (size_t)kROWS * kDM;       // 8192*2048
    float* xh    = xz   + (size_t)kROWS * 2 * kDI;   // 8192*1024
    float* dbl   = xh   + (size_t)kROWS * kDI;       // 8192*64
    float* dty   = dbl  + (size_t)kROWS * 64;        // 8192*1024
    float* score = dty  + (size_t)kROWS * kDI;       // 8192
    float* smw   = score + kROWS;                    // 8192
    float* zcat  = smw  + kROWS;                     // 4096

    init_h_k<<<kROWS * kDM / 256, 256, 0, stream>>>(x, h);

    for (int l = 0; l < kL; l++) {
        const float *f_n1w = fp[0]  + l * kDM,            *b_n1w = bp[0]  + l * kDM;
        const float *f_n1b = fp[1]  + l * kDM,            *b_n1b = bp[1]  + l * kDM;
        const float *f_inw = fp[2]  + l * kDM * 2 * kDI,  *b_inw = bp[2]  + l * kDM * 2 * kDI;
        const float *f_cw  = fp[3]  + l * kDI * kDC,      *b_cw  = bp[3]  + l * kDI * kDC;
        const float *f_cb  = fp[4]  + l * kDI,            *b_cb  = bp[4]  + l * kDI;
        const float *f_xpw = fp[5]  + l * kDI * 64,       *b_xpw = bp[5]  + l * kDI * 64;
        const float *f_dtw = fp[6]  + l * kDTR * kDI,     *b_dtw = bp[6]  + l * kDTR * kDI;
        const float *f_dtb = fp[7]  + l * kDI,            *b_dtb = bp[7]  + l * kDI;
        const float *f_alog= fp[8]  + l * kDI * kDS,      *b_alog= bp[8]  + l * kDI * kDS;
        const float *f_dd  = fp[9]  + l * kDI,            *b_dd  = bp[9]  + l * kDI;
        const float *f_ow  = fp[10] + l * kDI * kDM,      *b_ow  = bp[10] + l * kDI * kDM;
        const float *f_n2w = fp[11] + l * kDM,            *b_n2w = bp[11] + l * kDM;
        const float *f_n2b = fp[12] + l * kDM,            *b_n2b = bp[12] + l * kDM;
        const float *f_w1  = fp[13] + l * kDM * 4 * kDM,  *b_w1  = bp[13] + l * kDM * 4 * kDM;
        const float *f_b1  = fp[14] + l * 4 * kDM,        *b_b1  = bp[14] + l * 4 * kDM;
        const float *f_w2  = fp[15] + l * 4 * kDM * kDM,  *b_w2  = bp[15] + l * 4 * kDM * kDM;
        const float *f_b2  = fp[16] + l * kDM,            *b_b2  = bp[16] + l * kDM;

        // u = LN1(h)
        ln_k<kDM><<<kROWS, 256, 0, stream>>>(h, f_n1w, b_n1w, f_n1b, b_n1b, u);
        // xz = u @ in_w
        gemm_ep<128,128,8,8,8,EPI_NONE><<<dim3(2*kDI/128, kROWS/128), 256, 0, stream>>>(
            u, kDM, kDM, f_inw, b_inw, nullptr, nullptr, xz, 2*kDI);
        // xh = silu(causal depthwise conv(xz[:, :DI]) + cb)
        conv_silu_k<<<kROWS * kDI / 256, 256, 0, stream>>>(xz, f_cw, b_cw, f_cb, b_cb, xh);
        // dbl = xh @ xpw
        gemm_ep<64,64,16,4,4,EPI_NONE><<<dim3(64/64, kROWS/64), 256, 0, stream>>>(
            xh, kDI, kDI, f_xpw, b_xpw, nullptr, nullptr, dbl, 64);
        // dt = softplus(dbl[:, :32] @ dtw + dtb)
        gemm_ep<128,128,8,8,8,EPI_SOFTPLUS><<<dim3(kDI/128, kROWS/128), 256, 0, stream>>>(
            dbl, 64, kDTR, f_dtw, b_dtw, f_dtb, b_dtb, dty, kDI);
        // selective scan -> y (written into dead x-half of xz), gated by silu(z)
        scan_k<<<kB2 * kDI / 16, 256, 0, stream>>>(dty, xh, dbl, xz + kDI, xz,
                                                   f_alog, b_alog, f_dd, b_dd);
        // h += y @ ow   (y lives in xz with row stride 2*kDI)
        gemm_ep<128,128,8,8,8,EPI_RESID><<<dim3(kDM/128, kROWS/128), 256, 0, stream>>>(
            xz, 2*kDI, kDI, f_ow, b_ow, nullptr, nullptr, h, kDM);
        // u = LN2(h)
        ln_k<kDM><<<kROWS, 256, 0, stream>>>(h, f_n2w, b_n2w, f_n2b, b_n2b, u);
        // xz = gelu(u @ w1 + b1)
        gemm_ep<128,128,8,8,8,EPI_GELU><<<dim3(4*kDM/128, kROWS/128), 256, 0, stream>>>(
            u, kDM, kDM, f_w1, b_w1, f_b1, b_b1, xz, 4*kDM);
        // h += xz @ w2 + b2
        gemm_ep<128,128,8,8,8,EPI_RESID_BIAS><<<dim3(kDM/128, kROWS/128), 256, 0, stream>>>(
            xz, 4*kDM, 4*kDM, f_w2, b_w2, f_b2, b_b2, h, kDM);
    }

    // attention scores: u[:, :256] = tanh(h @ aw1 + ab1)
    gemm_ep<128,128,8,8,8,EPI_TANH><<<dim3(256/128, kROWS/128), 256, 0, stream>>>(
        h, kDM, kDM, aw1, aw1, ab1, ab1, u, 256);
    att_score_k<<<kROWS, 64, 0, stream>>>(u, aw2, ab2, score);
    softmax_k<<<kB2, 256, 0, stream>>>(score, smw);
    hipMemsetAsync(zcat, 0, kB * 2 * kDM * sizeof(float), stream);
    pool_k<<<dim3(kB2, 32), 512, 0, stream>>>(smw, h, zcat);
    // out[0:4096] = LN(concat(zf, zb))
    ln_k<2*kDM><<<kB, 256, 0, stream>>>(zcat, nw, nw, nb, nb, out);
    // out[4096:8192] = 0.5*(af + flip(ab))
    att_out_k<<<kB * kN / 256, 256, 0, stream>>>(smw, out + kB * 2 * kDM);
}

// Round 3
// 1417.832 us; speedup vs baseline: 2.8455x; 1.9516x over previous
//
#include <hip/hip_runtime.h>
#include <math.h>

constexpr int kDM   = 512;
constexpr int kDI   = 1024;
constexpr int kDS   = 16;
constexpr int kDC   = 4;
constexpr int kDTR  = 32;
constexpr int kL    = 2;
constexpr int kB    = 4;
constexpr int kN    = 1024;
constexpr int kB2   = 8;              // combined batch: rows 0-3 fwd, 4-7 bwd
constexpr int kROWS = kB2 * kN;       // 8192
constexpr int kMDIR = kB * kN;        // 4096 rows per direction

enum { EPI_NONE=0, EPI_SOFTPLUS=1, EPI_RESID=2, EPI_GELU=3, EPI_RESID_BIAS=4, EPI_TANH=5 };

typedef __attribute__((ext_vector_type(8))) short bf16x8;
typedef __attribute__((ext_vector_type(4))) short bf16x4;
typedef __attribute__((ext_vector_type(4))) float f32x4;

__device__ __forceinline__ unsigned short f2bf(float f) {
    unsigned int u = __float_as_uint(f);
    return (unsigned short)((u + 0x7FFFu + ((u >> 16) & 1u)) >> 16);
}

// ---------------------------------------------------------------- init h ----
__global__ __launch_bounds__(256) void init_h_k(const float* __restrict__ x,
                                                float* __restrict__ h)
{
    size_t idx = (size_t)blockIdx.x * 256 + threadIdx.x;   // kROWS*kDM
    int d  = idx & (kDM - 1);
    int t  = (idx >> 9) & (kN - 1);
    int bb = (int)(idx >> 19);
    int b = bb & 3, dir = bb >> 2;
    int ts = dir ? (kN - 1 - t) : t;
    h[idx] = x[((size_t)b * kN + ts) * kDM + d];
}

// ---------------------------------------------------------------- layernorm --
template<int DIM>
__global__ __launch_bounds__(256) void ln_k(const float* __restrict__ x,
    const float* __restrict__ wf, const float* __restrict__ wb,
    const float* __restrict__ bf, const float* __restrict__ bbp,
    float* __restrict__ out)
{
    const int row = blockIdx.x;
    const int tid = threadIdx.x;
    constexpr int PT = DIM / 256;
    const int dir = (row >= kMDIR) ? 1 : 0;
    const float* w = dir ? wb : wf;
    const float* b = dir ? bbp : bf;

    float v[PT];
    float s1 = 0.f, s2 = 0.f;
#pragma unroll
    for (int i = 0; i < PT; i++) {
        float t = x[(size_t)row * DIM + tid + i * 256];
        v[i] = t; s1 += t; s2 += t * t;
    }
    for (int o = 32; o > 0; o >>= 1) { s1 += __shfl_xor(s1, o, 64); s2 += __shfl_xor(s2, o, 64); }
    __shared__ float r1[4], r2[4];
    int wv = tid >> 6;
    if ((tid & 63) == 0) { r1[wv] = s1; r2[wv] = s2; }
    __syncthreads();
    s1 = r1[0] + r1[1] + r1[2] + r1[3];
    s2 = r2[0] + r2[1] + r2[2] + r2[3];
    float mu  = s1 / DIM;
    float var = s2 / DIM - mu * mu;
    float rr  = rsqrtf(var + 1e-5f);
#pragma unroll
    for (int i = 0; i < PT; i++) {
        int c = tid + i * 256;
        out[(size_t)row * DIM + c] = (v[i] - mu) * rr * w[c] + b[c];
    }
}

// ---------------------------------------------------------------- MFMA GEMM -
// C[M x N] = A[M x K (lda), fp32] @ B[K x N, fp32] (+bias)(+epilogue).
// A: fp32 -> bf16 staged to padded LDS [m][k] (stride 40 elems; b128 frag
//    reads land 2 lanes/bank = free per m136).
// B: fp32 row-major, staged with in-register 4x4 transpose into [n][k] LDS.
// MFMA: v_mfma_f32_16x16x32_bf16; A frag A[m=lane&15][k=quad*8+j];
//       B frag B^T[n=lane&15][k=quad*8+j]; C/D row=quad*4+reg, col=lane&15.
template<int BM, int BN, int EPI>
__global__ __launch_bounds__(256) void gemm_mfma(
    const float* __restrict__ A, int lda, int K,
    const float* __restrict__ Bf, const float* __restrict__ Bbk,
    const float* __restrict__ biasf, const float* __restrict__ biasb,
    float* __restrict__ C, int N)
{
    constexpr int BK  = 32;
    constexpr int SK  = 40;              // padded LDS row stride in bf16 elems
    constexpr int WM  = BM / 2, WN = BN / 2;
    constexpr int MT  = WM / 16, NT = WN / 16;
    constexpr int NB4 = BN / 4;
    constexpr int AR  = (BM * 4) / 256;  // A staging rounds (slots of 8 floats)

    __shared__ unsigned short As[BM * SK];
    __shared__ unsigned short Bs[BN * SK];

    const int tid  = threadIdx.x;
    const int n0   = blockIdx.x * BN;
    const int row0 = blockIdx.y * BM;
    const int dir  = (row0 >= kMDIR) ? 1 : 0;
    const float* __restrict__ Bg = dir ? Bbk : Bf;
    const float* bias = dir ? biasb : biasf;

    const int lane = tid & 63;
    const int wave = tid >> 6;
    const int wr = wave >> 1, wc = wave & 1;
    const int ml = lane & 15, q = lane >> 4;

    f32x4 acc[MT][NT];
#pragma unroll
    for (int i = 0; i < MT; i++)
#pragma unroll
        for (int j = 0; j < NT; j++)
#pragma unroll
            for (int r = 0; r < 4; r++) acc[i][j][r] = 0.f;

    const bool bact = tid < NB4 * 8;
    const int  nb   = tid & (NB4 - 1);
    const int  kb   = tid / NB4;

    for (int kt = 0; kt < K; kt += BK) {
        // ---- global loads (overlap with previous iteration's MFMA) ----
        float4 a_ld[2][2];
#pragma unroll
        for (int r = 0; r < AR; r++) {
            int i = tid + r * 256;
            int m = i >> 2, c = i & 3;
            const float* gp = A + (size_t)(row0 + m) * lda + kt + c * 8;
            a_ld[r][0] = *(const float4*)gp;
            a_ld[r][1] = *(const float4*)(gp + 4);
        }
        float b_ld[4][4];
        if (bact) {
#pragma unroll
            for (int j = 0; j < 4; j++) {
                float4 f = *(const float4*)(Bg + (size_t)(kt + kb * 4 + j) * N + n0 + nb * 4);
                b_ld[j][0] = f.x; b_ld[j][1] = f.y; b_ld[j][2] = f.z; b_ld[j][3] = f.w;
            }
        }
        __syncthreads();     // previous iteration's LDS reads complete
        // ---- LDS writes ----
#pragma unroll
        for (int r = 0; r < AR; r++) {
            int i = tid + r * 256;
            int m = i >> 2, c = i & 3;
            union { unsigned short u[8]; bf16x8 v; } t;
            t.u[0] = f2bf(a_ld[r][0].x); t.u[1] = f2bf(a_ld[r][0].y);
            t.u[2] = f2bf(a_ld[r][0].z); t.u[3] = f2bf(a_ld[r][0].w);
            t.u[4] = f2bf(a_ld[r][1].x); t.u[5] = f2bf(a_ld[r][1].y);
            t.u[6] = f2bf(a_ld[r][1].z); t.u[7] = f2bf(a_ld[r][1].w);
            *(bf16x8*)&As[m * SK + c * 8] = t.v;
        }
        if (bact) {
#pragma unroll
            for (int np = 0; np < 4; np++) {
                union { unsigned short u[4]; bf16x4 v; } t;
#pragma unroll
                for (int j = 0; j < 4; j++) t.u[j] = f2bf(b_ld[j][np]);
                *(bf16x4*)&Bs[(nb * 4 + np) * SK + kb * 4] = t.v;
            }
        }
        __syncthreads();
        // ---- fragments + MFMA ----
        bf16x8 af[MT], bfr[NT];
#pragma unroll
        for (int i = 0; i < MT; i++)
            af[i] = *(bf16x8*)&As[(wr * WM + i * 16 + ml) * SK + q * 8];
#pragma unroll
        for (int j = 0; j < NT; j++)
            bfr[j] = *(bf16x8*)&Bs[(wc * WN + j * 16 + ml) * SK + q * 8];
#pragma unroll
        for (int i = 0; i < MT; i++)
#pragma unroll
            for (int j = 0; j < NT; j++)
                acc[i][j] = __builtin_amdgcn_mfma_f32_16x16x32_bf16(af[i], bfr[j], acc[i][j], 0, 0, 0);
    }

    // ---- epilogue ----
#pragma unroll
    for (int j = 0; j < NT; j++) {
        int col = n0 + wc * WN + j * 16 + ml;
        float bv = 0.f;
        if (EPI == EPI_SOFTPLUS || EPI == EPI_GELU || EPI == EPI_RESID_BIAS || EPI == EPI_TANH)
            bv = bias[col];
#pragma unroll
        for (int i = 0; i < MT; i++) {
            int rw = row0 + wr * WM + i * 16 + q * 4;
#pragma unroll
            for (int r = 0; r < 4; r++) {
                float v = acc[i][j][r] + bv;
                size_t o = (size_t)(rw + r) * N + col;
                if      (EPI == EPI_NONE)       C[o] = v;
                else if (EPI == EPI_SOFTPLUS)   C[o] = (v > 20.f) ? v : __logf(1.f + __expf(v));
                else if (EPI == EPI_RESID)      C[o] += v;
                else if (EPI == EPI_RESID_BIAS) C[o] += v;
                else if (EPI == EPI_GELU)       C[o] = 0.5f * v * (1.f + erff(v * 0.70710678118654752f));
                else if (EPI == EPI_TANH)       C[o] = tanhf(v);
            }
        }
    }
}

// ---------------------------------------------------------------- conv+silu -
__global__ __launch_bounds__(256) void conv_silu_k(const float* __restrict__ xz,
    const float* __restrict__ cwf, const float* __restrict__ cwb,
    const float* __restrict__ cbf, const float* __restrict__ cbb,
    float* __restrict__ xh)
{
    size_t idx = (size_t)blockIdx.x * 256 + threadIdx.x;  // kROWS*kDI
    int d  = idx & (kDI - 1);
    int t  = (idx >> 10) & (kN - 1);
    int bb = (int)(idx >> 20);
    int dir = bb >> 2;
    const float* cw = dir ? cwb : cwf;
    const float* cb = dir ? cbb : cbf;
    float acc = cb[d];
    long long base = ((long long)bb * kN + t) * (2 * kDI) + d;
#pragma unroll
    for (int k = 0; k < kDC; k++) {
        int ts = t - (kDC - 1) + k;
        if (ts >= 0)
            acc += cw[d * kDC + k] * xz[base + (long long)(k - (kDC - 1)) * (2 * kDI)];
    }
    xh[idx] = acc * (1.f / (1.f + __expf(-acc)));
}

// ---------------------------------------------------------------- scan ------
constexpr int kTC = 8;            // timesteps prefetched per chunk
constexpr int kNC = kN / kTC;     // 128 chunks

struct ScanChunk { float dt[kTC], xv[kTC], Bv[kTC], Cv[kTC], zv[kTC]; };

template<int CTRL>
__device__ __forceinline__ float dpp_add(float x) {
    int m = __builtin_amdgcn_update_dpp(0, __float_as_int(x), CTRL, 0xF, 0xF, true);
    return x + __int_as_float(m);
}

__device__ __forceinline__ void scan_load(
    const float* __restrict__ dtp, const float* __restrict__ xh,
    const float* __restrict__ dbl, const float* __restrict__ zsrc,
    size_t rbase, int t0, int d, int s, ScanChunk& ck)
{
#pragma unroll
    for (int j = 0; j < kTC; j++) {
        size_t row = rbase + t0 + j;
        ck.dt[j] = dtp[row * kDI + d];
        ck.xv[j] = xh[row * kDI + d];
        ck.Bv[j] = dbl[row * 64 + kDTR + s];
        ck.Cv[j] = dbl[row * 64 + kDTR + kDS + s];
        ck.zv[j] = zsrc[row * (2 * kDI) + d];
    }
}

__device__ __forceinline__ void scan_compute(
    float* __restrict__ ybuf, size_t rbase, int t0, int d, int s,
    float a, float ddv, float& hst, const ScanChunk& ck)
{
#pragma unroll
    for (int j = 0; j < kTC; j++) {
        float e = __expf(ck.dt[j] * a);
        hst = e * hst + (ck.dt[j] * ck.xv[j]) * ck.Bv[j];
        float p = hst * ck.Cv[j];
        p = dpp_add<0x128>(p);   // row_ror:8  (16-lane row == s-group)
        p = dpp_add<0x124>(p);   // row_ror:4
        p = dpp_add<0x122>(p);   // row_ror:2
        p = dpp_add<0x121>(p);   // row_ror:1
        if (s == 0) {
            float zv = ck.zv[j];
            size_t row = rbase + t0 + j;
            ybuf[row * (2 * kDI) + d] = (p + ddv * ck.xv[j]) * (zv / (1.f + __expf(-zv)));
        }
    }
}

__global__ __launch_bounds__(256) void scan_k(
    const float* __restrict__ dtp, const float* __restrict__ xh,
    const float* __restrict__ dbl, const float* __restrict__ zsrc,
    float* __restrict__ ybuf,
    const float* __restrict__ alogf, const float* __restrict__ alogb,
    const float* __restrict__ ddf,   const float* __restrict__ ddb)
{
    int blk  = blockIdx.x;            // 512 blocks
    int bb   = blk >> 6;
    int dgrp = blk & 63;
    int s    = threadIdx.x & 15;
    int d    = dgrp * 16 + (threadIdx.x >> 4);
    int dir  = bb >> 2;
    const float* alog = dir ? alogb : alogf;
    const float* ddp  = dir ? ddb : ddf;
    float a   = -__expf(alog[d * kDS + s]);
    float ddv = ddp[d];
    float hst = 0.f;
    size_t rbase = (size_t)bb * kN;

    ScanChunk cka, ckb;
    scan_load(dtp, xh, dbl, zsrc, rbase, 0, d, s, cka);
    for (int c = 0; c < kNC; c += 2) {
        scan_load(dtp, xh, dbl, zsrc, rbase, (c + 1) * kTC, d, s, ckb);
        scan_compute(ybuf, rbase, c * kTC, d, s, a, ddv, hst, cka);
        int tn = (c + 2 < kNC) ? (c + 2) * kTC : (kNC - 1) * kTC;  // clamped dummy on last
        scan_load(dtp, xh, dbl, zsrc, rbase, tn, d, s, cka);
        scan_compute(ybuf, rbase, (c + 1) * kTC, d, s, a, ddv, hst, ckb);
    }
}

// ---------------------------------------------------------------- attention -
__global__ __launch_bounds__(64) void att_score_k(const float* __restrict__ tmp,
    const float* __restrict__ aw2, const float* __restrict__ ab2,
    float* __restrict__ score)
{
    int row = blockIdx.x, lane = threadIdx.x;
    float acc = 0.f;
#pragma unroll
    for (int j = 0; j < 4; j++)
        acc += tmp[(size_t)row * 256 + lane + j * 64] * aw2[lane + j * 64];
    for (int o = 32; o > 0; o >>= 1) acc += __shfl_xor(acc, o, 64);
    if (lane == 0) score[row] = acc + ab2[0];
}

__global__ __launch_bounds__(256) void softmax_k(const float* __restrict__ score,
                                                 float* __restrict__ w)
{
    int bb = blockIdx.x, tid = threadIdx.x;
    float v[4]; float m = -1e30f;
#pragma unroll
    for (int i = 0; i < 4; i++) { v[i] = score[bb * kN + tid + i * 256]; m = fmaxf(m, v[i]); }
    for (int o = 32; o > 0; o >>= 1) m = fmaxf(m, __shfl_xor(m, o, 64));
    __shared__ float r1[4], r2[4];
    int wv = tid >> 6;
    if ((tid & 63) == 0) r1[wv] = m;
    __syncthreads();
    m = fmaxf(fmaxf(r1[0], r1[1]), fmaxf(r1[2], r1[3]));
    float s = 0.f;
#pragma unroll
    for (int i = 0; i < 4; i++) { v[i] = __expf(v[i] - m); s += v[i]; }
    for (int o = 32; o > 0; o >>= 1) s += __shfl_xor(s, o, 64);
    if ((tid & 63) == 0) r2[wv] = s;
    __syncthreads();
    s = r2[0] + r2[1] + r2[2] + r2[3];
    float inv = 1.f / s;
#pragma unroll
    for (int i = 0; i < 4; i++) w[bb * kN + tid + i * 256] = v[i] * inv;
}

__global__ __launch_bounds__(512) void pool_k(const float* __restrict__ w,
    const float* __restrict__ h, float* zcat)
{
    int bb = blockIdx.x, chunk = blockIdx.y;   // 8 x 32
    int d = threadIdx.x;
    float acc = 0.f;
    int n0 = chunk * 32;
    for (int n = n0; n < n0 + 32; n++)
        acc += w[bb * kN + n] * h[((size_t)bb * kN + n) * kDM + d];
    int b = bb & 3, dir = bb >> 2;
    atomicAdd(&zcat[b * (2 * kDM) + dir * kDM + d], acc);
}

__global__ __launch_bounds__(256) void att_out_k(const float* __restrict__ w,
                                                 float* __restrict__ out)
{
    int idx = blockIdx.x * 256 + threadIdx.x;  // kB*kN
    int b = idx >> 10, n = idx & 1023;
    out[idx] = 0.5f * (w[b * kN + n] + w[(b + 4) * kN + (kN - 1 - n)]);
}

// ---------------------------------------------------------------- launch ----
extern "C" void kernel_launch(void* const* d_in, const int* in_sizes, int n_in,
                              void* d_out, int out_size, void* d_ws, size_t ws_size,
                              hipStream_t stream)
{
    const float* x = (const float*)d_in[0];
    const float* fp[17]; const float* bp[17];
    for (int i = 0; i < 17; i++) { fp[i] = (const float*)d_in[1 + i]; bp[i] = (const float*)d_in[18 + i]; }
    const float* aw1 = (const float*)d_in[35];
    const float* ab1 = (const float*)d_in[36];
    const float* aw2 = (const float*)d_in[37];
    const float* ab2 = (const float*)d_in[38];
    const float* nw  = (const float*)d_in[39];
    const float* nb  = (const float*)d_in[40];
    float* out = (float*)d_out;

    float* ws    = (float*)d_ws;
    float* h     = ws;                               // 8192*512
    float* u     = h    + (size_t)kROWS * kDM;       // 8192*512
    float* xz    = u    + (size_t)kROWS * kDM;       // 8192*2048
    float* xh    = xz   + (size_t)kROWS * 2 * kDI;   // 8192*1024
    float* dbl   = xh   + (size_t)kROWS * kDI;       // 8192*64
    float* dty   = dbl  + (size_t)kROWS * 64;        // 8192*1024
    float* score = dty  + (size_t)kROWS * kDI;       // 8192
    float* smw   = score + kROWS;                    // 8192
    float* zcat  = smw  + kROWS;                     // 4096

    init_h_k<<<kROWS * kDM / 256, 256, 0, stream>>>(x, h);

    for (int l = 0; l < kL; l++) {
        const float *f_n1w = fp[0]  + l * kDM,            *b_n1w = bp[0]  + l * kDM;
        const float *f_n1b = fp[1]  + l * kDM,            *b_n1b = bp[1]  + l * kDM;
        const float *f_inw = fp[2]  + l * kDM * 2 * kDI,  *b_inw = bp[2]  + l * kDM * 2 * kDI;
        const float *f_cw  = fp[3]  + l * kDI * kDC,      *b_cw  = bp[3]  + l * kDI * kDC;
        const float *f_cb  = fp[4]  + l * kDI,            *b_cb  = bp[4]  + l * kDI;
        const float *f_xpw = fp[5]  + l * kDI * 64,       *b_xpw = bp[5]  + l * kDI * 64;
        const float *f_dtw = fp[6]  + l * kDTR * kDI,     *b_dtw = bp[6]  + l * kDTR * kDI;
        const float *f_dtb = fp[7]  + l * kDI,            *b_dtb = bp[7]  + l * kDI;
        const float *f_alog= fp[8]  + l * kDI * kDS,      *b_alog= bp[8]  + l * kDI * kDS;
        const float *f_dd  = fp[9]  + l * kDI,            *b_dd  = bp[9]  + l * kDI;
        const float *f_ow  = fp[10] + l * kDI * kDM,      *b_ow  = bp[10] + l * kDI * kDM;
        const float *f_n2w = fp[11] + l * kDM,            *b_n2w = bp[11] + l * kDM;
        const float *f_n2b = fp[12] + l * kDM,            *b_n2b = bp[12] + l * kDM;
        const float *f_w1  = fp[13] + l * kDM * 4 * kDM,  *b_w1  = bp[13] + l * kDM * 4 * kDM;
        const float *f_b1  = fp[14] + l * 4 * kDM,        *b_b1  = bp[14] + l * 4 * kDM;
        const float *f_w2  = fp[15] + l * 4 * kDM * kDM,  *b_w2  = bp[15] + l * 4 * kDM * kDM;
        const float *f_b2  = fp[16] + l * kDM,            *b_b2  = bp[16] + l * kDM;

        // u = LN1(h)
        ln_k<kDM><<<kROWS, 256, 0, stream>>>(h, f_n1w, b_n1w, f_n1b, b_n1b, u);
        // xz = u @ in_w
        gemm_mfma<128,128,EPI_NONE><<<dim3(2*kDI/128, kROWS/128), 256, 0, stream>>>(
            u, kDM, kDM, f_inw, b_inw, nullptr, nullptr, xz, 2*kDI);
        // xh = silu(causal depthwise conv(xz[:, :DI]) + cb)
        conv_silu_k<<<kROWS * kDI / 256, 256, 0, stream>>>(xz, f_cw, b_cw, f_cb, b_cb, xh);
        // dbl = xh @ xpw
        gemm_mfma<64,64,EPI_NONE><<<dim3(1, kROWS/64), 256, 0, stream>>>(
            xh, kDI, kDI, f_xpw, b_xpw, nullptr, nullptr, dbl, 64);
        // dt = softplus(dbl[:, :32] @ dtw + dtb)
        gemm_mfma<128,128,EPI_SOFTPLUS><<<dim3(kDI/128, kROWS/128), 256, 0, stream>>>(
            dbl, 64, kDTR, f_dtw, b_dtw, f_dtb, b_dtb, dty, kDI);
        // selective scan -> y (written into dead x-half of xz), gated by silu(z)
        scan_k<<<kB2 * kDI / 16, 256, 0, stream>>>(dty, xh, dbl, xz + kDI, xz,
                                                   f_alog, b_alog, f_dd, b_dd);
        // h += y @ ow   (y lives in xz with row stride 2*kDI)
        gemm_mfma<128,128,EPI_RESID><<<dim3(kDM/128, kROWS/128), 256, 0, stream>>>(
            xz, 2*kDI, kDI, f_ow, b_ow, nullptr, nullptr, h, kDM);
        // u = LN2(h)
        ln_k<kDM><<<kROWS, 256, 0, stream>>>(h, f_n2w, b_n2w, f_n2b, b_n2b, u);
        // xz = gelu(u @ w1 + b1)
        gemm_mfma<128,128,EPI_GELU><<<dim3(4*kDM/128, kROWS/128), 256, 0, stream>>>(
            u, kDM, kDM, f_w1, b_w1, f_b1, b_b1, xz, 4*kDM);
        // h += xz @ w2 + b2
        gemm_mfma<128,128,EPI_RESID_BIAS><<<dim3(kDM/128, kROWS/128), 256, 0, stream>>>(
            xz, 4*kDM, 4*kDM, f_w2, b_w2, f_b2, b_b2, h, kDM);
    }

    // attention scores: u[:, :256] = tanh(h @ aw1 + ab1)
    gemm_mfma<128,128,EPI_TANH><<<dim3(256/128, kROWS/128), 256, 0, stream>>>(
        h, kDM, kDM, aw1, aw1, ab1, ab1, u, 256);
    att_score_k<<<kROWS, 64, 0, stream>>>(u, aw2, ab2, score);
    softmax_k<<<kB2, 256, 0, stream>>>(score, smw);
    hipMemsetAsync(zcat, 0, kB * 2 * kDM * sizeof(float), stream);
    pool_k<<<dim3(kB2, 32), 512, 0, stream>>>(smw, h, zcat);
    // out[0:4096] = LN(concat(zf, zb))
    ln_k<2*kDM><<<kB, 256, 0, stream>>>(zcat, nw, nw, nb, nb, out);
    // out[4096:8192] = 0.5*(af + flip(ab))
    att_out_k<<<kB * kN / 256, 256, 0, stream>>>(smw, out + kB * 2 * kDM);
}

// Round 4
// 1362.850 us; speedup vs baseline: 2.9603x; 1.0403x over previous
//
#include <hip/hip_runtime.h>
#include <math.h>

constexpr int kDM   = 512;
constexpr int kDI   = 1024;
constexpr int kDS   = 16;
constexpr int kDC   = 4;
constexpr int kDTR  = 32;
constexpr int kL    = 2;
constexpr int kB    = 4;
constexpr int kN    = 1024;
constexpr int kB2   = 8;              // combined batch: rows 0-3 fwd, 4-7 bwd
constexpr int kROWS = kB2 * kN;       // 8192
constexpr int kMDIR = kB * kN;        // 4096 rows per direction

enum { EPI_NONE=0, EPI_SOFTPLUS=1, EPI_RESID=2, EPI_GELU=3, EPI_RESID_BIAS=4, EPI_TANH=5 };
enum { MODE_N=0, MODE_OTR=1, MODE_DBL=2, MODE_GATE=3 };

typedef __attribute__((ext_vector_type(8))) short bf16x8;
typedef __attribute__((ext_vector_type(4))) short bf16x4;
typedef __attribute__((ext_vector_type(4))) float f32x4;

__device__ __forceinline__ unsigned short f2bf(float f) {
    unsigned int u = __float_as_uint(f);
    return (unsigned short)((u + 0x7FFFu + ((u >> 16) & 1u)) >> 16);
}

// ---------------------------------------------------------------- init h ----
__global__ __launch_bounds__(256) void init_h_k(const float* __restrict__ x,
                                                float* __restrict__ h)
{
    size_t idx = (size_t)blockIdx.x * 256 + threadIdx.x;   // kROWS*kDM
    int d  = idx & (kDM - 1);
    int t  = (idx >> 9) & (kN - 1);
    int bb = (int)(idx >> 19);
    int b = bb & 3, dir = bb >> 2;
    int ts = dir ? (kN - 1 - t) : t;
    h[idx] = x[((size_t)b * kN + ts) * kDM + d];
}

// ---------------------------------------------------------------- layernorm --
template<int DIM>
__global__ __launch_bounds__(256) void ln_k(const float* __restrict__ x,
    const float* __restrict__ wf, const float* __restrict__ wb,
    const float* __restrict__ bf, const float* __restrict__ bbp,
    float* __restrict__ out)
{
    const int row = blockIdx.x;
    const int tid = threadIdx.x;
    constexpr int PT = DIM / 256;
    const int dir = (row >= kMDIR) ? 1 : 0;
    const float* w = dir ? wb : wf;
    const float* b = dir ? bbp : bf;

    float v[PT];
    float s1 = 0.f, s2 = 0.f;
#pragma unroll
    for (int i = 0; i < PT; i++) {
        float t = x[(size_t)row * DIM + tid + i * 256];
        v[i] = t; s1 += t; s2 += t * t;
    }
    for (int o = 32; o > 0; o >>= 1) { s1 += __shfl_xor(s1, o, 64); s2 += __shfl_xor(s2, o, 64); }
    __shared__ float r1[4], r2[4];
    int wv = tid >> 6;
    if ((tid & 63) == 0) { r1[wv] = s1; r2[wv] = s2; }
    __syncthreads();
    s1 = r1[0] + r1[1] + r1[2] + r1[3];
    s2 = r2[0] + r2[1] + r2[2] + r2[3];
    float mu  = s1 / DIM;
    float var = s2 / DIM - mu * mu;
    float rr  = rsqrtf(var + 1e-5f);
#pragma unroll
    for (int i = 0; i < PT; i++) {
        int c = tid + i * 256;
        out[(size_t)row * DIM + c] = (v[i] - mu) * rr * w[c] + b[c];
    }
}

// ---------------------------------------------------------------- MFMA GEMM -
// C[M x N] = A @ B (+bias)(+epilogue). All fp32 in memory, bf16 MFMA compute.
// A: normal = row-major [M][lda]; ATR=1 -> At[K][lda] (lda = M stride),
//    staged with 4x4 in-register transpose (same structure as B staging).
// B: fp32 row-major [K][N], staged transposed into [n][k] LDS.
// MODE_N:   normal stores (EPI_RESID* accumulate into C).
// MODE_OTR: transposed-only output Ct[col*kROWS + row] (float4 over rows).
// MODE_DBL: normal + cols>=32 also transposed into Ct (dblT slice).
// MODE_GATE:cols<kDI normal into C; cols>=kDI silu()+transposed into Ct.
template<int BM, int BN, int EPI, int ATR, int MODE>
__global__ __launch_bounds__(256) void gemm_mfma(
    const float* __restrict__ A, int lda, int K,
    const float* __restrict__ Bf, const float* __restrict__ Bbk,
    const float* __restrict__ biasf, const float* __restrict__ biasb,
    float* __restrict__ C, int ldc, int N, float* __restrict__ Ct)
{
    constexpr int BK  = 32;
    constexpr int SK  = 40;              // padded LDS row stride in bf16 elems
    constexpr int WM  = BM / 2, WN = BN / 2;
    constexpr int MT  = WM / 16, NT = WN / 16;
    constexpr int NB4 = BN / 4;
    constexpr int MB4 = BM / 4;
    constexpr int AR  = (BM * 4) / 256;  // A staging rounds (slots of 8 floats)

    __shared__ unsigned short As[BM * SK];
    __shared__ unsigned short Bs[BN * SK];

    const int tid  = threadIdx.x;
    const int n0   = blockIdx.x * BN;
    const int row0 = blockIdx.y * BM;
    const int dir  = (row0 >= kMDIR) ? 1 : 0;
    const float* __restrict__ Bg = dir ? Bbk : Bf;
    const float* bias = dir ? biasb : biasf;

    const int lane = tid & 63;
    const int wave = tid >> 6;
    const int wr = wave >> 1, wc = wave & 1;
    const int ml = lane & 15, q = lane >> 4;

    f32x4 acc[MT][NT];
#pragma unroll
    for (int i = 0; i < MT; i++)
#pragma unroll
        for (int j = 0; j < NT; j++)
#pragma unroll
            for (int r = 0; r < 4; r++) acc[i][j][r] = 0.f;

    const bool bact = tid < NB4 * 8;
    const int  nb   = tid & (NB4 - 1);
    const int  kb   = tid / NB4;
    const bool aact = tid < MB4 * 8;     // for ATR staging
    const int  mb   = tid & (MB4 - 1);
    const int  ka   = tid / MB4;

    for (int kt = 0; kt < K; kt += BK) {
        // ---- global loads ----
        float4 a_ld[AR][2];
        float at_ld[4][4];
        if (!ATR) {
#pragma unroll
            for (int r = 0; r < AR; r++) {
                int i = tid + r * 256;
                int m = i >> 2, c = i & 3;
                const float* gp = A + (size_t)(row0 + m) * lda + kt + c * 8;
                a_ld[r][0] = *(const float4*)gp;
                a_ld[r][1] = *(const float4*)(gp + 4);
            }
        } else if (aact) {
#pragma unroll
            for (int j = 0; j < 4; j++) {
                float4 f = *(const float4*)(A + (size_t)(kt + ka * 4 + j) * lda + row0 + mb * 4);
                at_ld[j][0] = f.x; at_ld[j][1] = f.y; at_ld[j][2] = f.z; at_ld[j][3] = f.w;
            }
        }
        float b_ld[4][4];
        if (bact) {
#pragma unroll
            for (int j = 0; j < 4; j++) {
                float4 f = *(const float4*)(Bg + (size_t)(kt + kb * 4 + j) * N + n0 + nb * 4);
                b_ld[j][0] = f.x; b_ld[j][1] = f.y; b_ld[j][2] = f.z; b_ld[j][3] = f.w;
            }
        }
        __syncthreads();     // previous iteration's LDS reads complete
        // ---- LDS writes ----
        if (!ATR) {
#pragma unroll
            for (int r = 0; r < AR; r++) {
                int i = tid + r * 256;
                int m = i >> 2, c = i & 3;
                union { unsigned short u[8]; bf16x8 v; } t;
                t.u[0] = f2bf(a_ld[r][0].x); t.u[1] = f2bf(a_ld[r][0].y);
                t.u[2] = f2bf(a_ld[r][0].z); t.u[3] = f2bf(a_ld[r][0].w);
                t.u[4] = f2bf(a_ld[r][1].x); t.u[5] = f2bf(a_ld[r][1].y);
                t.u[6] = f2bf(a_ld[r][1].z); t.u[7] = f2bf(a_ld[r][1].w);
                *(bf16x8*)&As[m * SK + c * 8] = t.v;
            }
        } else if (aact) {
#pragma unroll
            for (int mp = 0; mp < 4; mp++) {
                union { unsigned short u[4]; bf16x4 v; } t;
#pragma unroll
                for (int j = 0; j < 4; j++) t.u[j] = f2bf(at_ld[j][mp]);
                *(bf16x4*)&As[(mb * 4 + mp) * SK + ka * 4] = t.v;
            }
        }
        if (bact) {
#pragma unroll
            for (int np = 0; np < 4; np++) {
                union { unsigned short u[4]; bf16x4 v; } t;
#pragma unroll
                for (int j = 0; j < 4; j++) t.u[j] = f2bf(b_ld[j][np]);
                *(bf16x4*)&Bs[(nb * 4 + np) * SK + kb * 4] = t.v;
            }
        }
        __syncthreads();
        // ---- fragments + MFMA ----
        bf16x8 af[MT], bfr[NT];
#pragma unroll
        for (int i = 0; i < MT; i++)
            af[i] = *(bf16x8*)&As[(wr * WM + i * 16 + ml) * SK + q * 8];
#pragma unroll
        for (int j = 0; j < NT; j++)
            bfr[j] = *(bf16x8*)&Bs[(wc * WN + j * 16 + ml) * SK + q * 8];
#pragma unroll
        for (int i = 0; i < MT; i++)
#pragma unroll
            for (int j = 0; j < NT; j++)
                acc[i][j] = __builtin_amdgcn_mfma_f32_16x16x32_bf16(af[i], bfr[j], acc[i][j], 0, 0, 0);
    }

    // ---- epilogue ----
#pragma unroll
    for (int j = 0; j < NT; j++) {
        int col = n0 + wc * WN + j * 16 + ml;
        float bv = 0.f;
        if (EPI == EPI_SOFTPLUS || EPI == EPI_GELU || EPI == EPI_RESID_BIAS || EPI == EPI_TANH)
            bv = bias[col];
#pragma unroll
        for (int i = 0; i < MT; i++) {
            int rw = row0 + wr * WM + i * 16 + q * 4;
            float4 v4;
            float* vp = &v4.x;
#pragma unroll
            for (int r = 0; r < 4; r++) {
                float v = acc[i][j][r] + bv;
                if (EPI == EPI_SOFTPLUS) v = (v > 20.f) ? v : __logf(1.f + __expf(v));
                if (EPI == EPI_GELU)     v = 0.5f * v * (1.f + erff(v * 0.70710678118654752f));
                if (EPI == EPI_TANH)     v = tanhf(v);
                vp[r] = v;
            }
            if (MODE == MODE_OTR) {
                *(float4*)&Ct[(size_t)col * kROWS + rw] = v4;
            } else if (MODE == MODE_GATE && n0 >= kDI) {
#pragma unroll
                for (int r = 0; r < 4; r++) vp[r] = vp[r] / (1.f + __expf(-vp[r]));
                *(float4*)&Ct[(size_t)(col - kDI) * kROWS + rw] = v4;
            } else {
#pragma unroll
                for (int r = 0; r < 4; r++) {
                    size_t o = (size_t)(rw + r) * ldc + col;
                    if (EPI == EPI_RESID || EPI == EPI_RESID_BIAS) C[o] += vp[r];
                    else C[o] = vp[r];
                }
                if (MODE == MODE_DBL && col >= 32)
                    *(float4*)&Ct[(size_t)(col - 32) * kROWS + rw] = v4;
            }
        }
    }
}

// ---------------------------------------------------------------- conv ------
// xb[row][kDI] (x-half) -> xhT[d][row] = silu(causal conv + bias), transposed.
__global__ __launch_bounds__(256) void conv_t_k(const float* __restrict__ xb,
    const float* __restrict__ cwf, const float* __restrict__ cwb,
    const float* __restrict__ cbf, const float* __restrict__ cbb,
    float* __restrict__ xhT)
{
    __shared__ float tl[67][33];
    const int t0 = blockIdx.x * 64, d0 = blockIdx.y * 32, bb = blockIdx.z;
    const int dir = bb >> 2;
    const float* cw = dir ? cwb : cwf;
    const float* cb = dir ? cbb : cbf;
    const int dl = threadIdx.x & 31, rl = threadIdx.x >> 5;
    const size_t base = (size_t)bb * kN * kDI + d0 + dl;
#pragma unroll
    for (int p = 0; p < 9; p++) {
        int r = p * 8 + rl;
        if (r < 67) {
            int ts = t0 + r - 3;
            tl[r][dl] = (ts >= 0) ? xb[base + (size_t)ts * kDI] : 0.f;
        }
    }
    __syncthreads();
    const int gd = d0 + dl;
    float c0 = cw[gd*4+0], c1 = cw[gd*4+1], c2 = cw[gd*4+2], c3 = cw[gd*4+3];
    float bv = cb[gd];
    float o[8];
#pragma unroll
    for (int jj = 0; jj < 8; jj++) {
        int tt = rl + 8 * jj;
        float acc = bv + c0*tl[tt][dl] + c1*tl[tt+1][dl] + c2*tl[tt+2][dl] + c3*tl[tt+3][dl];
        o[jj] = acc / (1.f + __expf(-acc));
    }
    __syncthreads();
#pragma unroll
    for (int jj = 0; jj < 8; jj++) tl[rl + 8 * jj][dl] = o[jj];
    __syncthreads();
    const int tb = threadIdx.x & 63, dg = threadIdx.x >> 6;
#pragma unroll
    for (int dd = 0; dd < 8; dd++) {
        int d2 = dg * 8 + dd;
        xhT[(size_t)(d0 + d2) * kROWS + (size_t)bb * kN + t0 + tb] = tl[tb][d2];
    }
}

// ---------------------------------------------------------------- scan ------
// All operands transposed: [d][t] / [s][t], contiguous in t -> float4 loads.
// gate = silu(z) precomputed by in_w GEMM epilogue.
constexpr int kTC = 16;           // timesteps per chunk
constexpr int kNC = kN / kTC;     // 64 chunks

struct ScanChunk { float dt[kTC], xv[kTC], gv[kTC], Bv[kTC], Cv[kTC]; };

template<int CTRL>
__device__ __forceinline__ float dpp_add(float x) {
    int m = __builtin_amdgcn_update_dpp(0, __float_as_int(x), CTRL, 0xF, 0xF, true);
    return x + __int_as_float(m);
}

__device__ __forceinline__ void scan_load(
    const float* __restrict__ pdt, const float* __restrict__ pxh,
    const float* __restrict__ pgv, const float* __restrict__ pB,
    const float* __restrict__ pC, int t0, ScanChunk& ck)
{
#pragma unroll
    for (int j = 0; j < kTC; j += 4) {
        *(float4*)&ck.dt[j] = *(const float4*)(pdt + t0 + j);
        *(float4*)&ck.xv[j] = *(const float4*)(pxh + t0 + j);
        *(float4*)&ck.gv[j] = *(const float4*)(pgv + t0 + j);
        *(float4*)&ck.Bv[j] = *(const float4*)(pB + t0 + j);
        *(float4*)&ck.Cv[j] = *(const float4*)(pC + t0 + j);
    }
}

__device__ __forceinline__ void scan_compute(
    float* __restrict__ py, int t0, int s,
    float a, float ddv, float& hst, const ScanChunk& ck)
{
    float ya[kTC];
#pragma unroll
    for (int j = 0; j < kTC; j++) {
        float e = __expf(ck.dt[j] * a);
        hst = e * hst + (ck.dt[j] * ck.xv[j]) * ck.Bv[j];
        float p = hst * ck.Cv[j];
        p = dpp_add<0x128>(p);   // row_ror:8  (16-lane row == s-group)
        p = dpp_add<0x124>(p);   // row_ror:4
        p = dpp_add<0x122>(p);   // row_ror:2
        p = dpp_add<0x121>(p);   // row_ror:1
        ya[j] = (p + ddv * ck.xv[j]) * ck.gv[j];
    }
    if (s == 0) {
#pragma unroll
        for (int j = 0; j < kTC; j += 4)
            *(float4*)(py + t0 + j) = *(float4*)&ya[j];
    }
}

__global__ __launch_bounds__(256, 2) void scan_k(
    const float* __restrict__ dtT, const float* __restrict__ xhT,
    const float* __restrict__ gateT, const float* __restrict__ dblT,
    float* __restrict__ yT,
    const float* __restrict__ alogf, const float* __restrict__ alogb,
    const float* __restrict__ ddf,   const float* __restrict__ ddb)
{
    int blk  = blockIdx.x;            // 512 blocks
    int bb   = blk >> 6;
    int dgrp = blk & 63;
    int s    = threadIdx.x & 15;
    int d    = dgrp * 16 + (threadIdx.x >> 4);
    int dir  = bb >> 2;
    const float* alog = dir ? alogb : alogf;
    const float* ddp  = dir ? ddb : ddf;
    float a   = -__expf(alog[d * kDS + s]);
    float ddv = ddp[d];
    float hst = 0.f;
    const size_t tb = (size_t)bb * kN;

    const float* pdt = dtT   + (size_t)d * kROWS + tb;
    const float* pxh = xhT   + (size_t)d * kROWS + tb;
    const float* pgv = gateT + (size_t)d * kROWS + tb;
    const float* pB  = dblT  + (size_t)s * kROWS + tb;
    const float* pC  = dblT  + (size_t)(16 + s) * kROWS + tb;
    float*       py  = yT    + (size_t)d * kROWS + tb;

    ScanChunk cka, ckb;
    scan_load(pdt, pxh, pgv, pB, pC, 0, cka);
    for (int c = 0; c < kNC; c += 2) {
        scan_load(pdt, pxh, pgv, pB, pC, (c + 1) * kTC, ckb);
        scan_compute(py, c * kTC, s, a, ddv, hst, cka);
        int tn = (c + 2 < kNC) ? (c + 2) * kTC : (kNC - 1) * kTC;  // clamped dummy on last
        scan_load(pdt, pxh, pgv, pB, pC, tn, cka);
        scan_compute(py, (c + 1) * kTC, s, a, ddv, hst, ckb);
    }
}

// ---------------------------------------------------------------- attention -
__global__ __launch_bounds__(64) void att_score_k(const float* __restrict__ tmp,
    const float* __restrict__ aw2, const float* __restrict__ ab2,
    float* __restrict__ score)
{
    int row = blockIdx.x, lane = threadIdx.x;
    float acc = 0.f;
#pragma unroll
    for (int j = 0; j < 4; j++)
        acc += tmp[(size_t)row * 256 + lane + j * 64] * aw2[lane + j * 64];
    for (int o = 32; o > 0; o >>= 1) acc += __shfl_xor(acc, o, 64);
    if (lane == 0) score[row] = acc + ab2[0];
}

__global__ __launch_bounds__(256) void softmax_k(const float* __restrict__ score,
                                                 float* __restrict__ w)
{
    int bb = blockIdx.x, tid = threadIdx.x;
    float v[4]; float m = -1e30f;
#pragma unroll
    for (int i = 0; i < 4; i++) { v[i] = score[bb * kN + tid + i * 256]; m = fmaxf(m, v[i]); }
    for (int o = 32; o > 0; o >>= 1) m = fmaxf(m, __shfl_xor(m, o, 64));
    __shared__ float r1[4], r2[4];
    int wv = tid >> 6;
    if ((tid & 63) == 0) r1[wv] = m;
    __syncthreads();
    m = fmaxf(fmaxf(r1[0], r1[1]), fmaxf(r1[2], r1[3]));
    float s = 0.f;
#pragma unroll
    for (int i = 0; i < 4; i++) { v[i] = __expf(v[i] - m); s += v[i]; }
    for (int o = 32; o > 0; o >>= 1) s += __shfl_xor(s, o, 64);
    if ((tid & 63) == 0) r2[wv] = s;
    __syncthreads();
    s = r2[0] + r2[1] + r2[2] + r2[3];
    float inv = 1.f / s;
#pragma unroll
    for (int i = 0; i < 4; i++) w[bb * kN + tid + i * 256] = v[i] * inv;
}

__global__ __launch_bounds__(512) void pool_k(const float* __restrict__ w,
    const float* __restrict__ h, float* zcat)
{
    int bb = blockIdx.x, chunk = blockIdx.y;   // 8 x 32
    int d = threadIdx.x;
    float acc = 0.f;
    int n0 = chunk * 32;
    for (int n = n0; n < n0 + 32; n++)
        acc += w[bb * kN + n] * h[((size_t)bb * kN + n) * kDM + d];
    int b = bb & 3, dir = bb >> 2;
    atomicAdd(&zcat[b * (2 * kDM) + dir * kDM + d], acc);
}

__global__ __launch_bounds__(256) void att_out_k(const float* __restrict__ w,
                                                 float* __restrict__ out)
{
    int idx = blockIdx.x * 256 + threadIdx.x;  // kB*kN
    int b = idx >> 10, n = idx & 1023;
    out[idx] = 0.5f * (w[b * kN + n] + w[(b + 4) * kN + (kN - 1 - n)]);
}

// ---------------------------------------------------------------- launch ----
extern "C" void kernel_launch(void* const* d_in, const int* in_sizes, int n_in,
                              void* d_out, int out_size, void* d_ws, size_t ws_size,
                              hipStream_t stream)
{
    const float* x = (const float*)d_in[0];
    const float* fp[17]; const float* bp[17];
    for (int i = 0; i < 17; i++) { fp[i] = (const float*)d_in[1 + i]; bp[i] = (const float*)d_in[18 + i]; }
    const float* aw1 = (const float*)d_in[35];
    const float* ab1 = (const float*)d_in[36];
    const float* aw2 = (const float*)d_in[37];
    const float* ab2 = (const float*)d_in[38];
    const float* nw  = (const float*)d_in[39];
    const float* nb  = (const float*)d_in[40];
    float* out = (float*)d_out;

    float* ws    = (float*)d_ws;
    float* h     = ws;                               // 8192*512
    float* u     = h     + (size_t)kROWS * kDM;      // 8192*512
    float* xbuf  = u     + (size_t)kROWS * kDM;      // 8192*1024 (x-half; later yT; ffn1 spans xbuf+tbuf)
    float* tbuf  = xbuf  + (size_t)kROWS * kDI;      // 8192*1024 (dtT)
    float* xhT   = tbuf  + (size_t)kROWS * kDI;      // 1024*8192
    float* gateT = xhT   + (size_t)kROWS * kDI;      // 1024*8192
    float* dbl   = gateT + (size_t)kROWS * kDI;      // 8192*64
    float* dblT  = dbl   + (size_t)kROWS * 64;       // 32*8192
    float* score = dblT  + (size_t)32 * kROWS;       // 8192
    float* smw   = score + kROWS;                    // 8192
    float* zcat  = smw   + kROWS;                    // 4096

    init_h_k<<<kROWS * kDM / 256, 256, 0, stream>>>(x, h);

    for (int l = 0; l < kL; l++) {
        const float *f_n1w = fp[0]  + l * kDM,            *b_n1w = bp[0]  + l * kDM;
        const float *f_n1b = fp[1]  + l * kDM,            *b_n1b = bp[1]  + l * kDM;
        const float *f_inw = fp[2]  + l * kDM * 2 * kDI,  *b_inw = bp[2]  + l * kDM * 2 * kDI;
        const float *f_cw  = fp[3]  + l * kDI * kDC,      *b_cw  = bp[3]  + l * kDI * kDC;
        const float *f_cb  = fp[4]  + l * kDI,            *b_cb  = bp[4]  + l * kDI;
        const float *f_xpw = fp[5]  + l * kDI * 64,       *b_xpw = bp[5]  + l * kDI * 64;
        const float *f_dtw = fp[6]  + l * kDTR * kDI,     *b_dtw = bp[6]  + l * kDTR * kDI;
        const float *f_dtb = fp[7]  + l * kDI,            *b_dtb = bp[7]  + l * kDI;
        const float *f_alog= fp[8]  + l * kDI * kDS,      *b_alog= bp[8]  + l * kDI * kDS;
        const float *f_dd  = fp[9]  + l * kDI,            *b_dd  = bp[9]  + l * kDI;
        const float *f_ow  = fp[10] + l * kDI * kDM,      *b_ow  = bp[10] + l * kDI * kDM;
        const float *f_n2w = fp[11] + l * kDM,            *b_n2w = bp[11] + l * kDM;
        const float *f_n2b = fp[12] + l * kDM,            *b_n2b = bp[12] + l * kDM;
        const float *f_w1  = fp[13] + l * kDM * 4 * kDM,  *b_w1  = bp[13] + l * kDM * 4 * kDM;
        const float *f_b1  = fp[14] + l * 4 * kDM,        *b_b1  = bp[14] + l * 4 * kDM;
        const float *f_w2  = fp[15] + l * 4 * kDM * kDM,  *b_w2  = bp[15] + l * 4 * kDM * kDM;
        const float *f_b2  = fp[16] + l * kDM,            *b_b2  = bp[16] + l * kDM;

        // u = LN1(h)
        ln_k<kDM><<<kROWS, 256, 0, stream>>>(h, f_n1w, b_n1w, f_n1b, b_n1b, u);
        // x-half -> xbuf (normal); z-half -> gateT = silu(z) (transposed)
        gemm_mfma<128,128,EPI_NONE,0,MODE_GATE><<<dim3(2*kDI/128, kROWS/128), 256, 0, stream>>>(
            u, kDM, kDM, f_inw, b_inw, nullptr, nullptr, xbuf, kDI, 2*kDI, gateT);
        // xhT[d][row] = silu(conv(xbuf) + cb)
        conv_t_k<<<dim3(kN/64, kDI/32, kB2), 256, 0, stream>>>(
            xbuf, f_cw, b_cw, f_cb, b_cb, xhT);
        // dbl = xh @ xpw (A = xhT, transposed staging); cols 32..63 also -> dblT
        gemm_mfma<64,64,EPI_NONE,1,MODE_DBL><<<dim3(1, kROWS/64), 256, 0, stream>>>(
            xhT, kROWS, kDI, f_xpw, b_xpw, nullptr, nullptr, dbl, 64, 64, dblT);
        // dtT[d][row] = softplus(dbl[:, :32] @ dtw + dtb)
        gemm_mfma<128,128,EPI_SOFTPLUS,0,MODE_OTR><<<dim3(kDI/128, kROWS/128), 256, 0, stream>>>(
            dbl, 64, kDTR, f_dtw, b_dtw, f_dtb, b_dtb, nullptr, 0, kDI, tbuf);
        // selective scan -> yT (into xbuf; xbuf's xz content dead after conv)
        scan_k<<<kB2 * kDI / 16, 256, 0, stream>>>(tbuf, xhT, gateT, dblT, xbuf,
                                                   f_alog, b_alog, f_dd, b_dd);
        // h += y @ ow   (A = yT, transposed staging)
        gemm_mfma<128,128,EPI_RESID,1,MODE_N><<<dim3(kDM/128, kROWS/128), 256, 0, stream>>>(
            xbuf, kROWS, kDI, f_ow, b_ow, nullptr, nullptr, h, kDM, kDM, nullptr);
        // u = LN2(h)
        ln_k<kDM><<<kROWS, 256, 0, stream>>>(h, f_n2w, b_n2w, f_n2b, b_n2b, u);
        // ffn1: gelu(u @ w1 + b1) -> xbuf+tbuf region (8192 x 2048)
        gemm_mfma<128,128,EPI_GELU,0,MODE_N><<<dim3(4*kDM/128, kROWS/128), 256, 0, stream>>>(
            u, kDM, kDM, f_w1, b_w1, f_b1, b_b1, xbuf, 4*kDM, 4*kDM, nullptr);
        // h += ffn1 @ w2 + b2
        gemm_mfma<128,128,EPI_RESID_BIAS,0,MODE_N><<<dim3(kDM/128, kROWS/128), 256, 0, stream>>>(
            xbuf, 4*kDM, 4*kDM, f_w2, b_w2, f_b2, b_b2, h, kDM, kDM, nullptr);
    }

    // attention scores: u[:, :256] = tanh(h @ aw1 + ab1)
    gemm_mfma<128,128,EPI_TANH,0,MODE_N><<<dim3(256/128, kROWS/128), 256, 0, stream>>>(
        h, kDM, kDM, aw1, aw1, ab1, ab1, u, 256, 256, nullptr);
    att_score_k<<<kROWS, 64, 0, stream>>>(u, aw2, ab2, score);
    softmax_k<<<kB2, 256, 0, stream>>>(score, smw);
    hipMemsetAsync(zcat, 0, kB * 2 * kDM * sizeof(float), stream);
    pool_k<<<dim3(kB2, 32), 512, 0, stream>>>(smw, h, zcat);
    // out[0:4096] = LN(concat(zf, zb))
    ln_k<2*kDM><<<kB, 256, 0, stream>>>(zcat, nw, nw, nb, nb, out);
    // out[4096:8192] = 0.5*(af + flip(ab))
    att_out_k<<<kB * kN / 256, 256, 0, stream>>>(smw, out + kB * 2 * kDM);
}